// Round 4
// baseline (116.258 us; speedup 1.0000x reference)
//
#include <hip/hip_runtime.h>

// Problem constants (from reference)
#define NNODES 10000
#define DDEG   64
#define NEDGES 32768
#define FIN    64
#define HID    256

typedef __attribute__((ext_vector_type(8))) __bf16 bf16x8;
typedef __attribute__((ext_vector_type(4))) float  f32x4;

__device__ __forceinline__ unsigned short f2bf(float f) {
    unsigned x = __float_as_uint(f);
    return (unsigned short)((x + 0x7FFFu + ((x >> 16) & 1u)) >> 16);  // RNE
}
__device__ __forceinline__ float b2f(unsigned short u) {
    return __uint_as_float(((unsigned)u) << 16);
}

// Transposed-weight workspace layout (bf16 elements): WT[n][k] = W[k][n]
#define OFF_XIJ1 0        // [256][64]
#define OFF_XIJ2 16384    // [256][256]
#define OFF_XCN1 81920    // [256][64]
#define OFF_XCN2 98304    // [256][256]
#define OFF_XCN3 163840   // [256][256]
#define OFF_LIN1 229376   // [256][256]
#define WT_TOTAL 294912

// All 6 weight transposes (fp32 W[K,256] -> bf16 WT[256,K]) in ONE launch.
__global__ __launch_bounds__(256) void prep_k(const float* __restrict__ xij_w1,
                                              const float* __restrict__ xij_w2,
                                              const float* __restrict__ xcn_w1,
                                              const float* __restrict__ xcn_w2,
                                              const float* __restrict__ xcn_w3,
                                              const float* __restrict__ lin_w1,
                                              unsigned short* __restrict__ WT) {
    int idx = blockIdx.x * 256 + threadIdx.x;          // grid 1152 -> 294912
    const float* src;
    int r, ks;
    if (idx < OFF_XIJ2)      { r = idx - OFF_XIJ1; ks = 6; src = xij_w1; }
    else if (idx < OFF_XCN1) { r = idx - OFF_XIJ2; ks = 8; src = xij_w2; }
    else if (idx < OFF_XCN2) { r = idx - OFF_XCN1; ks = 6; src = xcn_w1; }
    else if (idx < OFF_XCN3) { r = idx - OFF_XCN2; ks = 8; src = xcn_w2; }
    else if (idx < OFF_LIN1) { r = idx - OFF_XCN3; ks = 8; src = xcn_w3; }
    else                     { r = idx - OFF_LIN1; ks = 8; src = lin_w1; }
    int n = r >> ks;
    int k = r & ((1 << ks) - 1);
    WT[idx] = f2bf(src[k * HID + n]);
}

// acc[2][4] (+)= A_lds[rows r0..r0+32)[K] @ WT[col-slice][K]^T (mfma 16x16x32 bf16).
// A-frag lane l: row = r0 + m*16 + (l&15), k = kk + 8*(l>>4) + i.
// LDS XOR swizzle: element ^= (row&7)<<3 (16B granular; 2-way max aliasing = free).
template <int K>
__device__ __forceinline__ void mfma_stage(const unsigned short* As,
                                           const unsigned short* __restrict__ Wt,
                                           int r0, int lr, int lg, int col0,
                                           f32x4 acc[2][4]) {
#pragma unroll
    for (int m = 0; m < 2; ++m)
#pragma unroll
        for (int n = 0; n < 4; ++n) acc[m][n] = (f32x4){0.f, 0.f, 0.f, 0.f};
    const int sw = (lr & 7) << 3;
#pragma unroll
    for (int kk = 0; kk < K; kk += 32) {
        bf16x8 a[2], b[4];
#pragma unroll
        for (int m = 0; m < 2; ++m)
            a[m] = *reinterpret_cast<const bf16x8*>(&As[(r0 + m * 16 + lr) * K + ((kk + 8 * lg) ^ sw)]);
#pragma unroll
        for (int n = 0; n < 4; ++n)
            b[n] = *reinterpret_cast<const bf16x8*>(&Wt[(col0 + n * 16 + lr) * K + kk + 8 * lg]);
#pragma unroll
        for (int m = 0; m < 2; ++m)
#pragma unroll
            for (int n = 0; n < 4; ++n)
                acc[m][n] = __builtin_amdgcn_mfma_f32_16x16x32_bf16(a[m], b[n], acc[m][n], 0, 0, 0);
    }
}

// Fused per-64-edge pipeline, 8 waves/block (512 threads).
// Wave wv: row group rg=wv>>2 (rows rg*32..+32), col group cg=wv&3 (cols cg*64..+64).
// D-frag lane l: row = r0 + m*16 + 4*(l>>4) + i, col = col0 + n*16 + (l&15).
__global__ __launch_bounds__(512) void fused_k(const float* __restrict__ x,
                                               const int* __restrict__ adj,
                                               const int* __restrict__ tar,
                                               const unsigned short* __restrict__ WT,
                                               const float* __restrict__ xij_b1,
                                               const float* __restrict__ xij_b2,
                                               const float* __restrict__ xcn_b1,
                                               const float* __restrict__ xcn_b2,
                                               const float* __restrict__ xcn_b3,
                                               const float* __restrict__ lin_b1,
                                               const float* __restrict__ lin_w2,
                                               const float* __restrict__ lin_b2,
                                               const float* __restrict__ beta,
                                               float* __restrict__ out) {
    __shared__ unsigned short sXij[64 * 64];   // 8 KB, swizzled
    __shared__ unsigned short sXcn[64 * 64];   // 8 KB, swizzled
    __shared__ unsigned short sH[64 * 256];    // 32 KB, swizzled, reused across stages
    __shared__ float sRed[4 * 64];             // 1 KB

    const int tid  = threadIdx.x;
    const int wv   = tid >> 6;
    const int lane = tid & 63;
    const int lr   = lane & 15;
    const int lg   = lane >> 4;
    const int r0   = (wv >> 2) * 32;
    const int col0 = (wv & 3) * 64;
    const int row0 = blockIdx.x * 64;

    // ---- edge stage: 8 edges per wave, 2-deep prefetch pipeline ----
    {
        const int e0 = row0 + wv * 8;
        int   ic = tar[e0];
        int   jc = tar[NEDGES + e0];
        int   ni_c = adj[ic * DDEG + lane];
        int   nj_c = adj[jc * DDEG + lane];
        float xi_c = x[ic * FIN + lane];
        float xj_c = x[jc * FIN + lane];
        for (int t = 0; t < 8; ++t) {
            int ni = ni_c, nj = nj_c;
            float xi = xi_c, xj = xj_c;
            if (t < 7) {
                int e = e0 + t + 1;
                int i2 = tar[e];
                int j2 = tar[NEDGES + e];
                ni_c = adj[i2 * DDEG + lane];
                nj_c = adj[j2 * DDEG + lane];
                xi_c = x[i2 * FIN + lane];
                xj_c = x[j2 * FIN + lane];
            }
            bool found = false;
#pragma unroll
            for (int b = 0; b < 64; ++b)
                found |= (ni == (int)__builtin_amdgcn_readlane(nj, b));
            unsigned long long m = __ballot(found);
            float acc = 0.f;
            while (m) {
                int a = __ffsll(m) - 1;
                m &= m - 1;
                int r = (int)__builtin_amdgcn_readlane(ni, a);
                acc += x[r * FIN + lane];
            }
            int el = wv * 8 + t;
            int sidx = el * FIN + (lane ^ ((el & 7) << 3));
            sXij[sidx] = f2bf(xi * xj);
            sXcn[sidx] = f2bf(acc);
        }
    }
    __syncthreads();

    f32x4 acc[2][4];
    float bl[4];

    // ---- S1: h1 = relu(xij @ xij_w1 + b1) -> sH ----
    mfma_stage<64>(sXij, WT + OFF_XIJ1, r0, lr, lg, col0, acc);
#pragma unroll
    for (int n = 0; n < 4; ++n) bl[n] = xij_b1[col0 + n * 16 + lr];
#pragma unroll
    for (int m = 0; m < 2; ++m)
#pragma unroll
        for (int n = 0; n < 4; ++n)
#pragma unroll
            for (int i = 0; i < 4; ++i) {
                int row = r0 + m * 16 + 4 * lg + i;
                int col = col0 + n * 16 + lr;
                sH[row * HID + (col ^ ((row & 7) << 3))] = f2bf(fmaxf(acc[m][n][i] + bl[n], 0.f));
            }
    __syncthreads();

    // ---- S2: h_ij = h1 @ xij_w2 + b2 -> registers (packed bf16) ----
    mfma_stage<256>(sH, WT + OFF_XIJ2, r0, lr, lg, col0, acc);
#pragma unroll
    for (int n = 0; n < 4; ++n) bl[n] = xij_b2[col0 + n * 16 + lr];
    unsigned hij_lo[2][4], hij_hi[2][4];
#pragma unroll
    for (int m = 0; m < 2; ++m)
#pragma unroll
        for (int n = 0; n < 4; ++n) {
            hij_lo[m][n] = ((unsigned)f2bf(acc[m][n][1] + bl[n]) << 16) | f2bf(acc[m][n][0] + bl[n]);
            hij_hi[m][n] = ((unsigned)f2bf(acc[m][n][3] + bl[n]) << 16) | f2bf(acc[m][n][2] + bl[n]);
        }
    __syncthreads();   // S2 reads of sH done before S3 overwrites

    // ---- S3: t1 = relu(xcn @ xcn_w1 + b1) -> sH ----
    mfma_stage<64>(sXcn, WT + OFF_XCN1, r0, lr, lg, col0, acc);
#pragma unroll
    for (int n = 0; n < 4; ++n) bl[n] = xcn_b1[col0 + n * 16 + lr];
#pragma unroll
    for (int m = 0; m < 2; ++m)
#pragma unroll
        for (int n = 0; n < 4; ++n)
#pragma unroll
            for (int i = 0; i < 4; ++i) {
                int row = r0 + m * 16 + 4 * lg + i;
                int col = col0 + n * 16 + lr;
                sH[row * HID + (col ^ ((row & 7) << 3))] = f2bf(fmaxf(acc[m][n][i] + bl[n], 0.f));
            }
    __syncthreads();

    // ---- S4: t2 = relu(t1 @ xcn_w2 + b2) -> sH in place ----
    mfma_stage<256>(sH, WT + OFF_XCN2, r0, lr, lg, col0, acc);
    __syncthreads();   // all reads done before in-place overwrite
#pragma unroll
    for (int n = 0; n < 4; ++n) bl[n] = xcn_b2[col0 + n * 16 + lr];
#pragma unroll
    for (int m = 0; m < 2; ++m)
#pragma unroll
        for (int n = 0; n < 4; ++n)
#pragma unroll
            for (int i = 0; i < 4; ++i) {
                int row = r0 + m * 16 + 4 * lg + i;
                int col = col0 + n * 16 + lr;
                sH[row * HID + (col ^ ((row & 7) << 3))] = f2bf(fmaxf(acc[m][n][i] + bl[n], 0.f));
            }
    __syncthreads();

    // ---- S5: u = (t2 @ xcn_w3 + b3) * beta + h_ij -> sH in place ----
    mfma_stage<256>(sH, WT + OFF_XCN3, r0, lr, lg, col0, acc);
    __syncthreads();
#pragma unroll
    for (int n = 0; n < 4; ++n) bl[n] = xcn_b3[col0 + n * 16 + lr];
    const float betaf = beta[0];
#pragma unroll
    for (int m = 0; m < 2; ++m)
#pragma unroll
        for (int n = 0; n < 4; ++n) {
            float h0 = b2f((unsigned short)(hij_lo[m][n] & 0xFFFF));
            float h1 = b2f((unsigned short)(hij_lo[m][n] >> 16));
            float h2 = b2f((unsigned short)(hij_hi[m][n] & 0xFFFF));
            float h3 = b2f((unsigned short)(hij_hi[m][n] >> 16));
            float v0 = (acc[m][n][0] + bl[n]) * betaf + h0;
            float v1 = (acc[m][n][1] + bl[n]) * betaf + h1;
            float v2 = (acc[m][n][2] + bl[n]) * betaf + h2;
            float v3 = (acc[m][n][3] + bl[n]) * betaf + h3;
            int rb = r0 + m * 16 + 4 * lg;
            int col = col0 + n * 16 + lr;
            sH[(rb + 0) * HID + (col ^ (((rb + 0) & 7) << 3))] = f2bf(v0);
            sH[(rb + 1) * HID + (col ^ (((rb + 1) & 7) << 3))] = f2bf(v1);
            sH[(rb + 2) * HID + (col ^ (((rb + 2) & 7) << 3))] = f2bf(v2);
            sH[(rb + 3) * HID + (col ^ (((rb + 3) & 7) << 3))] = f2bf(v3);
        }
    __syncthreads();

    // ---- S6: out = relu(u @ lin_w1 + lb1) . lin_w2 + lb2 ----
    mfma_stage<256>(sH, WT + OFF_LIN1, r0, lr, lg, col0, acc);
#pragma unroll
    for (int n = 0; n < 4; ++n) bl[n] = lin_b1[col0 + n * 16 + lr];
    float w2l[4];
#pragma unroll
    for (int n = 0; n < 4; ++n) w2l[n] = lin_w2[col0 + n * 16 + lr];
#pragma unroll
    for (int m = 0; m < 2; ++m) {
        float p[4] = {0.f, 0.f, 0.f, 0.f};
#pragma unroll
        for (int n = 0; n < 4; ++n)
#pragma unroll
            for (int i = 0; i < 4; ++i)
                p[i] += fmaxf(acc[m][n][i] + bl[n], 0.f) * w2l[n];
#pragma unroll
        for (int i = 0; i < 4; ++i) {
            float s = p[i];
            s += __shfl_xor(s, 1);
            s += __shfl_xor(s, 2);
            s += __shfl_xor(s, 4);
            s += __shfl_xor(s, 8);
            if (lr == 0) sRed[(wv & 3) * 64 + r0 + m * 16 + 4 * lg + i] = s;
        }
    }
    __syncthreads();
    if (tid < 64)
        out[row0 + tid] = sRed[tid] + sRed[64 + tid] + sRed[128 + tid] + sRed[192 + tid] + lin_b2[0];
}

extern "C" void kernel_launch(void* const* d_in, const int* in_sizes, int n_in,
                              void* d_out, int out_size, void* d_ws, size_t ws_size,
                              hipStream_t stream) {
    const float* x      = (const float*)d_in[0];
    const int*   adj    = (const int*)d_in[1];
    const int*   tar    = (const int*)d_in[2];
    const float* beta   = (const float*)d_in[3];
    const float* xcn_w1 = (const float*)d_in[4];
    const float* xcn_b1 = (const float*)d_in[5];
    const float* xcn_w2 = (const float*)d_in[6];
    const float* xcn_b2 = (const float*)d_in[7];
    const float* xcn_w3 = (const float*)d_in[8];
    const float* xcn_b3 = (const float*)d_in[9];
    const float* xij_w1 = (const float*)d_in[10];
    const float* xij_b1 = (const float*)d_in[11];
    const float* xij_w2 = (const float*)d_in[12];
    const float* xij_b2 = (const float*)d_in[13];
    const float* lin_w1 = (const float*)d_in[14];
    const float* lin_b1 = (const float*)d_in[15];
    const float* lin_w2 = (const float*)d_in[16];
    const float* lin_b2 = (const float*)d_in[17];

    unsigned short* WT = (unsigned short*)d_ws;   // 294912 bf16 = 576 KiB

    prep_k<<<WT_TOTAL / 256, 256, 0, stream>>>(xij_w1, xij_w2, xcn_w1, xcn_w2, xcn_w3, lin_w1, WT);
    fused_k<<<NEDGES / 64, 512, 0, stream>>>(x, adj, tar, WT,
                                             xij_b1, xij_b2, xcn_b1, xcn_b2, xcn_b3,
                                             lin_b1, lin_w2, lin_b2, beta, (float*)d_out);
}

// Round 5
// 80.089 us; speedup vs baseline: 1.4516x; 1.4516x over previous
//
#include <hip/hip_runtime.h>

// Problem constants (from reference)
#define NNODES 10000
#define DDEG   64
#define NEDGES 32768
#define FIN    64
#define HID    256

typedef __attribute__((ext_vector_type(8))) __bf16 bf16x8;
typedef __attribute__((ext_vector_type(4))) float  f32x4;

__device__ __forceinline__ unsigned short f2bf(float f) {
    unsigned x = __float_as_uint(f);
    return (unsigned short)((x + 0x7FFFu + ((x >> 16) & 1u)) >> 16);  // RNE
}
__device__ __forceinline__ float b2f(unsigned short u) {
    return __uint_as_float(((unsigned)u) << 16);
}

// Transposed-weight workspace layout (bf16 elements): WT[n][k] = W[k][n]
#define OFF_XIJ1 0        // [256][64]
#define OFF_XIJ2 16384    // [256][256]
#define OFF_XCN1 81920    // [256][64]
#define OFF_XCN2 98304    // [256][256]
#define OFF_XCN3 163840   // [256][256]
#define OFF_LIN1 229376   // [256][256]
#define WT_TOTAL 294912

// All 6 weight transposes (fp32 W[K,256] -> bf16 WT[256,K]) in ONE launch.
__global__ __launch_bounds__(256) void prep_k(const float* __restrict__ xij_w1,
                                              const float* __restrict__ xij_w2,
                                              const float* __restrict__ xcn_w1,
                                              const float* __restrict__ xcn_w2,
                                              const float* __restrict__ xcn_w3,
                                              const float* __restrict__ lin_w1,
                                              unsigned short* __restrict__ WT) {
    int idx = blockIdx.x * 256 + threadIdx.x;          // grid 1152 -> 294912
    const float* src;
    int r, ks;
    if (idx < OFF_XIJ2)      { r = idx - OFF_XIJ1; ks = 6; src = xij_w1; }
    else if (idx < OFF_XCN1) { r = idx - OFF_XIJ2; ks = 8; src = xij_w2; }
    else if (idx < OFF_XCN2) { r = idx - OFF_XCN1; ks = 6; src = xcn_w1; }
    else if (idx < OFF_XCN3) { r = idx - OFF_XCN2; ks = 8; src = xcn_w2; }
    else if (idx < OFF_LIN1) { r = idx - OFF_XCN3; ks = 8; src = xcn_w3; }
    else                     { r = idx - OFF_LIN1; ks = 8; src = lin_w1; }
    int n = r >> ks;
    int k = r & ((1 << ks) - 1);
    WT[idx] = f2bf(src[k * HID + n]);
}

// acc[4][4] (+)= A_lds[64 rows][K] @ WT[col-slice][K]^T (mfma 16x16x32 bf16),
// with 2-deep prefetch of the global B-fragments (hides ~300-400cy L2 latency
// behind 16 MFMAs/iter). Fully unrolled -> all array indices compile-time.
// A-frag lane l: row = m*16 + (l&15), k = kk + 8*(l>>4) + i.
// LDS XOR swizzle: element ^= (row&7)<<3 (16B granular).
template <int K>
__device__ __forceinline__ void mfma_stage(const unsigned short* As,
                                           const unsigned short* __restrict__ Wt,
                                           int lr, int lg, int col0,
                                           f32x4 acc[4][4]) {
#pragma unroll
    for (int m = 0; m < 4; ++m)
#pragma unroll
        for (int n = 0; n < 4; ++n) acc[m][n] = (f32x4){0.f, 0.f, 0.f, 0.f};
    const int sw = (lr & 7) << 3;
    const unsigned short* pb[4];
#pragma unroll
    for (int n = 0; n < 4; ++n) pb[n] = Wt + (col0 + n * 16 + lr) * K + 8 * lg;

    bf16x8 bcur[4], bnxt[4];
#pragma unroll
    for (int n = 0; n < 4; ++n) bcur[n] = *reinterpret_cast<const bf16x8*>(pb[n]);

#pragma unroll
    for (int kk = 0; kk < K; kk += 32) {
        if (kk + 32 < K) {
#pragma unroll
            for (int n = 0; n < 4; ++n)
                bnxt[n] = *reinterpret_cast<const bf16x8*>(pb[n] + kk + 32);
        }
        bf16x8 a[4];
#pragma unroll
        for (int m = 0; m < 4; ++m)
            a[m] = *reinterpret_cast<const bf16x8*>(&As[(m * 16 + lr) * K + ((kk + 8 * lg) ^ sw)]);
#pragma unroll
        for (int m = 0; m < 4; ++m)
#pragma unroll
            for (int n = 0; n < 4; ++n)
                acc[m][n] = __builtin_amdgcn_mfma_f32_16x16x32_bf16(a[m], bcur[n], acc[m][n], 0, 0, 0);
        if (kk + 32 < K) {
#pragma unroll
            for (int n = 0; n < 4; ++n) bcur[n] = bnxt[n];
        }
    }
}

// Fused per-64-edge pipeline, 4 waves/block (256 threads).
// Wave wv owns output cols [wv*64, wv*64+64) over all 64 rows.
// D-frag lane l: row = m*16 + 4*(l>>4) + i, col = col0 + n*16 + (l&15).
__global__ __launch_bounds__(256) void fused_k(const float* __restrict__ x,
                                               const int* __restrict__ adj,
                                               const int* __restrict__ tar,
                                               const unsigned short* __restrict__ WT,
                                               unsigned* __restrict__ hij_g,
                                               const float* __restrict__ xij_b1,
                                               const float* __restrict__ xij_b2,
                                               const float* __restrict__ xcn_b1,
                                               const float* __restrict__ xcn_b2,
                                               const float* __restrict__ xcn_b3,
                                               const float* __restrict__ lin_b1,
                                               const float* __restrict__ lin_w2,
                                               const float* __restrict__ lin_b2,
                                               const float* __restrict__ beta,
                                               float* __restrict__ out) {
    __shared__ unsigned short sXij[64 * 64];   // 8 KB, swizzled
    __shared__ unsigned short sXcn[64 * 64];   // 8 KB, swizzled
    __shared__ unsigned short sH[64 * 256];    // 32 KB, swizzled, reused across stages
    __shared__ float sRed[4 * 64];             // 1 KB

    const int tid  = threadIdx.x;
    const int wv   = tid >> 6;
    const int lane = tid & 63;
    const int lr   = lane & 15;
    const int lg   = lane >> 4;
    const int col0 = wv * 64;
    const int row0 = blockIdx.x * 64;

    // ---- edge stage: 16 edges per wave, 2-deep prefetch pipeline ----
    {
        const int e0 = row0 + wv * 16;
        int   ic = tar[e0];
        int   jc = tar[NEDGES + e0];
        int   ni_c = adj[ic * DDEG + lane];
        int   nj_c = adj[jc * DDEG + lane];
        float xi_c = x[ic * FIN + lane];
        float xj_c = x[jc * FIN + lane];
        for (int t = 0; t < 16; ++t) {
            int ni = ni_c, nj = nj_c;
            float xi = xi_c, xj = xj_c;
            if (t < 15) {
                int e = e0 + t + 1;
                int i2 = tar[e];
                int j2 = tar[NEDGES + e];
                ni_c = adj[i2 * DDEG + lane];
                nj_c = adj[j2 * DDEG + lane];
                xi_c = x[i2 * FIN + lane];
                xj_c = x[j2 * FIN + lane];
            }
            bool found = false;
#pragma unroll
            for (int b = 0; b < 64; ++b)
                found |= (ni == (int)__builtin_amdgcn_readlane(nj, b));
            unsigned long long m = __ballot(found);
            float acc = 0.f;
            while (m) {
                int a = __ffsll(m) - 1;
                m &= m - 1;
                int r = (int)__builtin_amdgcn_readlane(ni, a);
                acc += x[r * FIN + lane];
            }
            int el = wv * 16 + t;
            int sidx = el * FIN + (lane ^ ((el & 7) << 3));
            sXij[sidx] = f2bf(xi * xj);
            sXcn[sidx] = f2bf(acc);
        }
    }
    __syncthreads();

    f32x4 acc[4][4];
    float bl[4];

    // ---- S1: h1 = relu(xij @ xij_w1 + b1) -> sH ----
    mfma_stage<64>(sXij, WT + OFF_XIJ1, lr, lg, col0, acc);
#pragma unroll
    for (int n = 0; n < 4; ++n) bl[n] = xij_b1[col0 + n * 16 + lr];
#pragma unroll
    for (int m = 0; m < 4; ++m)
#pragma unroll
        for (int n = 0; n < 4; ++n)
#pragma unroll
            for (int i = 0; i < 4; ++i) {
                int row = m * 16 + 4 * lg + i;
                int col = col0 + n * 16 + lr;
                sH[row * HID + (col ^ ((row & 7) << 3))] = f2bf(fmaxf(acc[m][n][i] + bl[n], 0.f));
            }
    __syncthreads();

    // ---- S2: h_ij = h1 @ xij_w2 + b2 -> hij_g (per-wave-private, coalesced) ----
    mfma_stage<256>(sH, WT + OFF_XIJ2, lr, lg, col0, acc);
#pragma unroll
    for (int n = 0; n < 4; ++n) bl[n] = xij_b2[col0 + n * 16 + lr];
    {
        unsigned* base = hij_g + (size_t)(blockIdx.x * 4 + wv) * 2048 + lane * 2;
#pragma unroll
        for (int m = 0; m < 4; ++m)
#pragma unroll
            for (int n = 0; n < 4; ++n) {
                unsigned lo = ((unsigned)f2bf(acc[m][n][1] + bl[n]) << 16) | f2bf(acc[m][n][0] + bl[n]);
                unsigned hi = ((unsigned)f2bf(acc[m][n][3] + bl[n]) << 16) | f2bf(acc[m][n][2] + bl[n]);
                base[(m * 4 + n) * 128 + 0] = lo;
                base[(m * 4 + n) * 128 + 1] = hi;
            }
    }
    __syncthreads();   // S2 reads of sH done before S3 overwrites

    // ---- S3: t1 = relu(xcn @ xcn_w1 + b1) -> sH ----
    mfma_stage<64>(sXcn, WT + OFF_XCN1, lr, lg, col0, acc);
#pragma unroll
    for (int n = 0; n < 4; ++n) bl[n] = xcn_b1[col0 + n * 16 + lr];
#pragma unroll
    for (int m = 0; m < 4; ++m)
#pragma unroll
        for (int n = 0; n < 4; ++n)
#pragma unroll
            for (int i = 0; i < 4; ++i) {
                int row = m * 16 + 4 * lg + i;
                int col = col0 + n * 16 + lr;
                sH[row * HID + (col ^ ((row & 7) << 3))] = f2bf(fmaxf(acc[m][n][i] + bl[n], 0.f));
            }
    __syncthreads();

    // ---- S4: t2 = relu(t1 @ xcn_w2 + b2) -> sH in place ----
    mfma_stage<256>(sH, WT + OFF_XCN2, lr, lg, col0, acc);
    __syncthreads();   // all reads done before in-place overwrite
#pragma unroll
    for (int n = 0; n < 4; ++n) bl[n] = xcn_b2[col0 + n * 16 + lr];
#pragma unroll
    for (int m = 0; m < 4; ++m)
#pragma unroll
        for (int n = 0; n < 4; ++n)
#pragma unroll
            for (int i = 0; i < 4; ++i) {
                int row = m * 16 + 4 * lg + i;
                int col = col0 + n * 16 + lr;
                sH[row * HID + (col ^ ((row & 7) << 3))] = f2bf(fmaxf(acc[m][n][i] + bl[n], 0.f));
            }
    __syncthreads();

    // ---- S5: u = (t2 @ xcn_w3 + b3) * beta + h_ij -> sH in place ----
    mfma_stage<256>(sH, WT + OFF_XCN3, lr, lg, col0, acc);
    __syncthreads();
#pragma unroll
    for (int n = 0; n < 4; ++n) bl[n] = xcn_b3[col0 + n * 16 + lr];
    const float betaf = beta[0];
    {
        const unsigned* base = hij_g + (size_t)(blockIdx.x * 4 + wv) * 2048 + lane * 2;
#pragma unroll
        for (int m = 0; m < 4; ++m)
#pragma unroll
            for (int n = 0; n < 4; ++n) {
                unsigned lo = base[(m * 4 + n) * 128 + 0];
                unsigned hi = base[(m * 4 + n) * 128 + 1];
                float h0 = b2f((unsigned short)(lo & 0xFFFF));
                float h1 = b2f((unsigned short)(lo >> 16));
                float h2 = b2f((unsigned short)(hi & 0xFFFF));
                float h3 = b2f((unsigned short)(hi >> 16));
                float v0 = (acc[m][n][0] + bl[n]) * betaf + h0;
                float v1 = (acc[m][n][1] + bl[n]) * betaf + h1;
                float v2 = (acc[m][n][2] + bl[n]) * betaf + h2;
                float v3 = (acc[m][n][3] + bl[n]) * betaf + h3;
                int rb = m * 16 + 4 * lg;
                int col = col0 + n * 16 + lr;
                sH[(rb + 0) * HID + (col ^ (((rb + 0) & 7) << 3))] = f2bf(v0);
                sH[(rb + 1) * HID + (col ^ (((rb + 1) & 7) << 3))] = f2bf(v1);
                sH[(rb + 2) * HID + (col ^ (((rb + 2) & 7) << 3))] = f2bf(v2);
                sH[(rb + 3) * HID + (col ^ (((rb + 3) & 7) << 3))] = f2bf(v3);
            }
    }
    __syncthreads();

    // ---- S6: out = relu(u @ lin_w1 + lb1) . lin_w2 + lb2 ----
    mfma_stage<256>(sH, WT + OFF_LIN1, lr, lg, col0, acc);
#pragma unroll
    for (int n = 0; n < 4; ++n) bl[n] = lin_b1[col0 + n * 16 + lr];
    float w2l[4];
#pragma unroll
    for (int n = 0; n < 4; ++n) w2l[n] = lin_w2[col0 + n * 16 + lr];
#pragma unroll
    for (int m = 0; m < 4; ++m) {
        float p[4] = {0.f, 0.f, 0.f, 0.f};
#pragma unroll
        for (int n = 0; n < 4; ++n)
#pragma unroll
            for (int i = 0; i < 4; ++i)
                p[i] += fmaxf(acc[m][n][i] + bl[n], 0.f) * w2l[n];
#pragma unroll
        for (int i = 0; i < 4; ++i) {
            float s = p[i];
            s += __shfl_xor(s, 1);
            s += __shfl_xor(s, 2);
            s += __shfl_xor(s, 4);
            s += __shfl_xor(s, 8);
            if (lr == 0) sRed[wv * 64 + m * 16 + 4 * lg + i] = s;
        }
    }
    __syncthreads();
    if (tid < 64)
        out[row0 + tid] = sRed[tid] + sRed[64 + tid] + sRed[128 + tid] + sRed[192 + tid] + lin_b2[0];
}

extern "C" void kernel_launch(void* const* d_in, const int* in_sizes, int n_in,
                              void* d_out, int out_size, void* d_ws, size_t ws_size,
                              hipStream_t stream) {
    const float* x      = (const float*)d_in[0];
    const int*   adj    = (const int*)d_in[1];
    const int*   tar    = (const int*)d_in[2];
    const float* beta   = (const float*)d_in[3];
    const float* xcn_w1 = (const float*)d_in[4];
    const float* xcn_b1 = (const float*)d_in[5];
    const float* xcn_w2 = (const float*)d_in[6];
    const float* xcn_b2 = (const float*)d_in[7];
    const float* xcn_w3 = (const float*)d_in[8];
    const float* xcn_b3 = (const float*)d_in[9];
    const float* xij_w1 = (const float*)d_in[10];
    const float* xij_b1 = (const float*)d_in[11];
    const float* xij_w2 = (const float*)d_in[12];
    const float* xij_b2 = (const float*)d_in[13];
    const float* lin_w1 = (const float*)d_in[14];
    const float* lin_b1 = (const float*)d_in[15];
    const float* lin_w2 = (const float*)d_in[16];
    const float* lin_b2 = (const float*)d_in[17];

    unsigned short* WT   = (unsigned short*)d_ws;            // 576 KiB
    unsigned*       hijg = (unsigned*)((char*)d_ws + 589824); // 16 MiB (bf16x2 packed)

    prep_k<<<WT_TOTAL / 256, 256, 0, stream>>>(xij_w1, xij_w2, xcn_w1, xcn_w2, xcn_w3, lin_w1, WT);
    fused_k<<<NEDGES / 64, 256, 0, stream>>>(x, adj, tar, WT, hijg,
                                             xij_b1, xij_b2, xcn_b1, xcn_b2, xcn_b3,
                                             lin_b1, lin_w2, lin_b2, beta, (float*)d_out);
}